// Round 10
// baseline (1260.608 us; speedup 1.0000x reference)
//
#include <hip/hip_runtime.h>
#include <math.h>

// ---------------------------------------------------------------------------
// ActorCriticPolicy fused forward — FP16 in/out, fp32 internal (R6+ verified).
//   E=100, H=256, L=4 res blocks, B=1024, A=256.
//   d_out: logits (1024x256 fp16) then value (1024 fp16).
//
// R10: BARRIER-FREE wave-owned-rows design (R9 post-mortem: spills fixed but
// MfmaUtil stuck at 12% — the 2-barriers-per-layer × 8-wave structure is the
// stall; see guide §5 "barrier drain"). Each wave owns 16 rows and computes
// all 256 cols (16 n-tiles, 64 acc VGPRs):
//   - LN is wave-local: 4x shfl_xor over the 16-lane col group. No LDS red.
//   - Activation tile is per-wave private LDS: ds_write -> ds_read ordering
//     is wave-lockstep + lgkmcnt. ZERO __syncthreads in the whole kernel.
//   - Logit dot / value head also wave-local.
// Cost: each wave streams the full B per layer from L2 (~6.3 GB total).
//
// Block: 256 thr = 4 waves = 64 rows. LDS 4x16x264 f16 = 33792 B -> 4 blk/CU.
// Fragment layouts (R7-verified): A: m=lane&15, k=(lane>>4)*8+j;
// B: n=lane&15, k=(lane>>4)*8+j; C/D: col=lane&15, row=(lane>>4)*4+reg.
//
// Packed layout (f16 units), per net [WIN | L0..L3 | W1head]:
//   policy: 0 win, 32768+l*65536 layers, W1@294912 (16 nt), W2@360448 (7 nt)
//   value:  base 389120: win, layers, W1@+294912 (8 nt). total 716800 f16.
// ---------------------------------------------------------------------------

typedef unsigned short u16;
typedef _Float16 f16;
typedef _Float16 half8 __attribute__((ext_vector_type(8)));
typedef float floatx4 __attribute__((ext_vector_type(4)));

#define E_DIM  100
#define H_DIM  256
#define NLAYER 4
#define BATCH  1024
#define NACT   256
#define NROWS_ACT (BATCH * NACT)
#define LN_EPS 1e-5f

#define NET_WL(l) (32768 + (l) * 65536)
#define NET_W1   294912
#define NET_W2P  360448
#define POL_SZ   389120
#define VAL_BASE POL_SZ
#define PACK_TOTAL (POL_SZ + 327680)

#define WS_VROWS   16
#define WS_ENCOBS  (16 + NROWS_ACT * 4)
#define WS_PACK    (WS_ENCOBS + BATCH * E_DIM * 4)

#define WAVE_H16 (16 * 264)

__device__ __forceinline__ u16 f2h_u16(float f) {
  union { u16 u; f16 h; } c; c.h = (f16)f; return c.u;
}

__global__ void zero_counter_kernel(int* counter) { *counter = 0; }

__global__ void compact_kernel(const int* __restrict__ mask, int n,
                               int* __restrict__ counter,
                               int* __restrict__ rows,
                               u16* __restrict__ logits)
{
  const int i = blockIdx.x * blockDim.x + threadIdx.x;
  if (i < n) {
    if (mask[i]) {
      const int p = atomicAdd(counter, 1);
      rows[p] = i;
    } else {
      logits[i] = (u16)0xFBFF;   // -65504, finite fp16 stand-in for -inf
    }
  }
}

__device__ __forceinline__ f16 pack_elem(const f16* __restrict__ W, int li,
                                         int K, int N, int Np)
{
  const int j = li & 7, lane = (li >> 3) & 63, tile = li >> 9;
  const int ntiles = Np >> 4;
  const int k0 = (tile / ntiles) * 32, n0 = (tile % ntiles) * 16;
  const int k = k0 + ((lane >> 4) << 3) + j, n = n0 + (lane & 15);
  return (k < K && n < N) ? W[k * N + n] : (f16)0.f;
}

__global__ void pack_all_kernel(
    const f16* __restrict__ pw_in, const f16* __restrict__ pW,
    const f16* __restrict__ po_w1, const f16* __restrict__ po_w2,
    const f16* __restrict__ vw_in, const f16* __restrict__ vW,
    const f16* __restrict__ vo_w1, f16* __restrict__ dst)
{
  const int i = blockIdx.x * blockDim.x + threadIdx.x;
  if (i >= PACK_TOTAL) return;
  f16 v;
  if (i < 32768)        v = pack_elem(pw_in, i, E_DIM, H_DIM, 256);
  else if (i < 294912) { const int r = i - 32768, l = r >> 16;
                         v = pack_elem(pW + (size_t)l * 65536, r & 65535, 256, 256, 256); }
  else if (i < 360448)  v = pack_elem(po_w1, i - 294912, 256, 256, 256);
  else if (i < 389120)  v = pack_elem(po_w2, i - 360448, 256, E_DIM, 112);
  else if (i < 421888)  v = pack_elem(vw_in, i - 389120, E_DIM, H_DIM, 256);
  else if (i < 684032) { const int r = i - 421888, l = r >> 16;
                         v = pack_elem(vW + (size_t)l * 65536, r & 65535, 256, 256, 256); }
  else                  v = pack_elem(vo_w1, i - 684032, 256, 128, 128);
  dst[i] = v;
}

// wave GEMM over this wave's private 16-row tile: NT n-tiles (of NTALL in the
// pack), KT k-steps of 32. All loads wave-local / L2; no barriers.
template <int NT, int KT, int NTALL>
__device__ __forceinline__ void wgemm(
    const f16* __restrict__ pw, const f16* __restrict__ h16w,
    int q, int l15, int lane, floatx4* acc)
{
  const f16* pl = pw + lane * 8;
#pragma unroll
  for (int k = 0; k < KT; ++k) {
    const half8 a = *(const half8*)(h16w + l15 * 264 + k * 32 + q * 8);
#pragma unroll
    for (int t = 0; t < NT; ++t) {
      const half8 b = *(const half8*)(pl + ((size_t)k * NTALL + t) * 512);
      acc[t] = __builtin_amdgcn_mfma_f32_16x16x32_f16(a, b, acc[t], 0, 0, 0);
    }
  }
}

// trunk: input layer + NLAYER residual layers, wave-local. R16: f16 residual.
template <bool R16>
__device__ __forceinline__ void run_trunk(
    const f16* __restrict__ packN,
    const f16* __restrict__ b_in, const f16* __restrict__ g_in, const f16* __restrict__ be_in,
    const f16* __restrict__ Br, const f16* __restrict__ Gr, const f16* __restrict__ Ber,
    f16* __restrict__ h16w, int q, int l15, int lane,
    floatx4 acc[16], float* __restrict__ resf, f16* __restrict__ res16)
{
#pragma unroll 1
  for (int l = 0; l <= NLAYER; ++l) {
    const f16 *pw, *bias, *g, *be;
    if (l == 0) { pw = packN; bias = b_in; g = g_in; be = be_in; }
    else {
      pw = packN + NET_WL(l - 1); bias = Br + (l - 1) * H_DIM;
      g = Gr + (l - 1) * H_DIM;   be = Ber + (l - 1) * H_DIM;
    }
#pragma unroll
    for (int t = 0; t < 16; ++t) {
      const float bv = (float)bias[t * 16 + l15];
      acc[t] = (floatx4){bv, bv, bv, bv};
    }
    if (l == 0) wgemm<16, 4, 16>(pw, h16w, q, l15, lane, acc);
    else        wgemm<16, 8, 16>(pw, h16w, q, l15, lane, acc);

    // wave-local LN over 256 cols for this lane's 4 rows (reg)
    float mean[4], rstd[4];
#pragma unroll
    for (int reg = 0; reg < 4; ++reg) {
      float s = 0.f, s2 = 0.f;
#pragma unroll
      for (int t = 0; t < 16; ++t) {
        const float v = fmaxf(acc[t][reg], 0.f);
        s += v; s2 += v * v;
      }
#pragma unroll
      for (int off = 1; off < 16; off <<= 1) {
        s  += __shfl_xor(s, off, 64);
        s2 += __shfl_xor(s2, off, 64);
      }
      mean[reg] = s * (1.f / 256.f);
      const float var = s2 * (1.f / 256.f) - mean[reg] * mean[reg];
      rstd[reg] = 1.f / sqrtf(var + LN_EPS);
    }
#pragma unroll
    for (int t = 0; t < 16; ++t) {
      const int col = t * 16 + l15;
      const float gv = (float)g[col], bev = (float)be[col];
#pragma unroll
      for (int reg = 0; reg < 4; ++reg) {
        const float v = (fmaxf(acc[t][reg], 0.f) - mean[reg]) * rstd[reg] * gv + bev;
        float rp;
        if (l == 0) rp = 0.f;
        else rp = R16 ? (float)res16[t * 4 + reg] : resf[t * 4 + reg];
        const float r = rp + v;
        if (R16) res16[t * 4 + reg] = (f16)r; else resf[t * 4 + reg] = r;
        h16w[(q * 4 + reg) * 264 + col] = (f16)r;
      }
    }
    // no barrier: wave-lockstep ds ordering suffices (private tile)
  }
}

// policy heads: h1 = relu(h@w1+b1) (written back to tile); enc = h1@w2+b2 in acc[0..6]
__device__ __forceinline__ void pol_heads(
    const f16* __restrict__ packN,
    const f16* __restrict__ b1, const f16* __restrict__ b2,
    f16* __restrict__ h16w, int q, int l15, int lane, floatx4 acc[16])
{
#pragma unroll
  for (int t = 0; t < 16; ++t) {
    const float bv = (float)b1[t * 16 + l15];
    acc[t] = (floatx4){bv, bv, bv, bv};
  }
  wgemm<16, 8, 16>(packN + NET_W1, h16w, q, l15, lane, acc);
#pragma unroll
  for (int t = 0; t < 16; ++t) {
    const int col = t * 16 + l15;
#pragma unroll
    for (int reg = 0; reg < 4; ++reg)
      h16w[(q * 4 + reg) * 264 + col] = (f16)fmaxf(acc[t][reg], 0.f);
  }
#pragma unroll
  for (int t = 0; t < 7; ++t) {
    const int col = t * 16 + l15;
    const float bv = (col < E_DIM) ? (float)b2[col] : 0.f;
    acc[t] = (floatx4){bv, bv, bv, bv};
  }
  wgemm<7, 8, 7>(packN + NET_W2P, h16w, q, l15, lane, acc);
}

// act-encode: compacted valid action rows -> logits. Barrier-free.
__global__ __launch_bounds__(256, 4)
void act_encode_kernel(
    const f16* __restrict__ xact,
    const int* __restrict__ vrows, const int* __restrict__ counter,
    const f16* __restrict__ packN,
    const f16* __restrict__ b_in, const f16* __restrict__ g_in, const f16* __restrict__ be_in,
    const f16* __restrict__ Br, const f16* __restrict__ Gr, const f16* __restrict__ Ber,
    const f16* __restrict__ b1, const f16* __restrict__ b2,
    const float* __restrict__ enc_obs_in,
    u16* __restrict__ logits)
{
  __shared__ __align__(16) f16 h16[4 * WAVE_H16];

  const int tid  = threadIdx.x;
  const int lane = tid & 63;
  const int w    = tid >> 6;
  const int base = blockIdx.x * 64;
  const int count = *counter;
  if (base >= count) return;

  const int l15 = lane & 15, q = lane >> 4;
  f16* h16w = h16 + w * WAVE_H16;
  const int wrow0 = base + w * 16;

  // wave-local staging of this wave's 16 rows (zero-padded cols >=100, OOB rows 0)
  for (int idx = lane; idx < 16 * 128; idx += 64) {
    const int r = idx >> 7, c = idx & 127;
    const int gr = wrow0 + r;
    f16 v = (f16)0.f;
    if (c < E_DIM && gr < count) v = xact[(size_t)vrows[gr] * E_DIM + c];
    h16w[r * 264 + c] = v;
  }

  floatx4 acc[16];
  f16 res16[64];
  run_trunk<true>(packN, b_in, g_in, be_in, Br, Gr, Ber, h16w, q, l15, lane,
                  acc, nullptr, res16);
  pol_heads(packN, b1, b2, h16w, q, l15, lane, acc);

  // wave-local logit dot: row = q*4+reg, col = t*16+l15
#pragma unroll
  for (int reg = 0; reg < 4; ++reg) {
    const int gr = wrow0 + q * 4 + reg;
    const bool ok = gr < count;
    const int vrow = ok ? vrows[gr] : 0;
    const int bb = vrow >> 8;   // A = 256
    float p = 0.f;
#pragma unroll
    for (int t = 0; t < 7; ++t) {
      const int col = t * 16 + l15;
      if (col < E_DIM)
        p += acc[t][reg] * enc_obs_in[(size_t)bb * E_DIM + col];
    }
#pragma unroll
    for (int off = 1; off < 16; off <<= 1) p += __shfl_xor(p, off, 64);
    if (ok && l15 == 0) logits[vrow] = f2h_u16(p * 0.1f);   // 1/sqrt(100)
  }
}

// merged: blocks 0..15 policy obs-encode -> enc_obs; 16..31 value net -> value
__global__ __launch_bounds__(256, 4)
void obs_value_kernel(
    const f16* __restrict__ obs,
    const f16* __restrict__ packP, const f16* __restrict__ packV,
    const f16* __restrict__ pb_in, const f16* __restrict__ pg_in, const f16* __restrict__ pbe_in,
    const f16* __restrict__ pB, const f16* __restrict__ pG, const f16* __restrict__ pBe,
    const f16* __restrict__ po_b1, const f16* __restrict__ po_b2,
    const f16* __restrict__ vb_in, const f16* __restrict__ vg_in, const f16* __restrict__ vbe_in,
    const f16* __restrict__ vB, const f16* __restrict__ vG, const f16* __restrict__ vBe,
    const f16* __restrict__ vo_b1, const f16* __restrict__ vo_b2, const f16* __restrict__ vo_w2,
    float* __restrict__ enc_obs_out, u16* __restrict__ value_out)
{
  __shared__ __align__(16) f16 h16[4 * WAVE_H16];

  const int tid  = threadIdx.x;
  const int lane = tid & 63;
  const int w    = tid >> 6;
  const bool isv = blockIdx.x >= 16;
  const int base = (isv ? (blockIdx.x - 16) : blockIdx.x) * 64;

  const int l15 = lane & 15, q = lane >> 4;
  f16* h16w = h16 + w * WAVE_H16;
  const int wrow0 = base + w * 16;

  for (int idx = lane; idx < 16 * 128; idx += 64) {
    const int r = idx >> 7, c = idx & 127;
    h16w[r * 264 + c] = (c < E_DIM) ? obs[(size_t)(wrow0 + r) * E_DIM + c] : (f16)0.f;
  }

  floatx4 acc[16];

  if (!isv) {
    f16 res16[64];
    run_trunk<true>(packP, pb_in, pg_in, pbe_in, pB, pG, pBe, h16w, q, l15, lane,
                    acc, nullptr, res16);
    pol_heads(packP, po_b1, po_b2, h16w, q, l15, lane, acc);
#pragma unroll
    for (int t = 0; t < 7; ++t) {
      const int col = t * 16 + l15;
      if (col < E_DIM) {
#pragma unroll
        for (int reg = 0; reg < 4; ++reg)
          enc_obs_out[(size_t)(wrow0 + q * 4 + reg) * E_DIM + col] = acc[t][reg];
      }
    }
  } else {
    float resf[64];
    run_trunk<false>(packV, vb_in, vg_in, vbe_in, vB, vG, vBe, h16w, q, l15, lane,
                     acc, resf, nullptr);
    // value head1: relu(h @ vo_w1 + vo_b1), N=128 (8 n-tiles)
#pragma unroll
    for (int t = 0; t < 8; ++t) {
      const float bv = (float)vo_b1[t * 16 + l15];
      acc[t] = (floatx4){bv, bv, bv, bv};
    }
    wgemm<8, 8, 8>(packV + NET_W1, h16w, q, l15, lane, acc);
    // head2: wave-local dot with vo_w2[128]
    float w2v[8];
#pragma unroll
    for (int t = 0; t < 8; ++t) w2v[t] = (float)vo_w2[t * 16 + l15];
    const float b2v = (float)vo_b2[0];
#pragma unroll
    for (int reg = 0; reg < 4; ++reg) {
      float p = 0.f;
#pragma unroll
      for (int t = 0; t < 8; ++t) p += fmaxf(acc[t][reg], 0.f) * w2v[t];
#pragma unroll
      for (int off = 1; off < 16; off <<= 1) p += __shfl_xor(p, off, 64);
      if (l15 == 0) value_out[wrow0 + q * 4 + reg] = f2h_u16(p + b2v);
    }
  }
}

// ============================ launch =======================================
extern "C" void kernel_launch(void* const* d_in, const int* in_sizes, int n_in,
                              void* d_out, int out_size, void* d_ws, size_t ws_size,
                              hipStream_t stream)
{
  const f16* obs   = (const f16*)d_in[0];
  const f16* actE  = (const f16*)d_in[1];
  const int* mask  = (const int*)d_in[2];
  const f16* pw_in = (const f16*)d_in[3];
  const f16* pb_in = (const f16*)d_in[4];
  const f16* pg_in = (const f16*)d_in[5];
  const f16* pbe_in= (const f16*)d_in[6];
  const f16* pW    = (const f16*)d_in[7];
  const f16* pB    = (const f16*)d_in[8];
  const f16* pG    = (const f16*)d_in[9];
  const f16* pBe   = (const f16*)d_in[10];
  const f16* po_w1 = (const f16*)d_in[11];
  const f16* po_b1 = (const f16*)d_in[12];
  const f16* po_w2 = (const f16*)d_in[13];
  const f16* po_b2 = (const f16*)d_in[14];
  const f16* vw_in = (const f16*)d_in[15];
  const f16* vb_in = (const f16*)d_in[16];
  const f16* vg_in = (const f16*)d_in[17];
  const f16* vbe_in= (const f16*)d_in[18];
  const f16* vW    = (const f16*)d_in[19];
  const f16* vB    = (const f16*)d_in[20];
  const f16* vG    = (const f16*)d_in[21];
  const f16* vBe   = (const f16*)d_in[22];
  const f16* vo_w1 = (const f16*)d_in[23];
  const f16* vo_b1 = (const f16*)d_in[24];
  const f16* vo_w2 = (const f16*)d_in[25];
  const f16* vo_b2 = (const f16*)d_in[26];

  u16* logits = (u16*)d_out;
  u16* value  = (u16*)d_out + NROWS_ACT;

  int*   counter = (int*)d_ws;
  int*   vrows   = (int*)((char*)d_ws + WS_VROWS);
  float* enc_obs = (float*)((char*)d_ws + WS_ENCOBS);
  f16*   packW   = (f16*)((char*)d_ws + WS_PACK);

  zero_counter_kernel<<<1, 1, 0, stream>>>(counter);
  compact_kernel<<<NROWS_ACT / 256, 256, 0, stream>>>(mask, NROWS_ACT, counter,
                                                      vrows, logits);
  pack_all_kernel<<<(PACK_TOTAL + 255) / 256, 256, 0, stream>>>(
      pw_in, pW, po_w1, po_w2, vw_in, vW, vo_w1, packW);

  obs_value_kernel<<<32, 256, 0, stream>>>(
      obs, packW, packW + VAL_BASE,
      pb_in, pg_in, pbe_in, pB, pG, pBe, po_b1, po_b2,
      vb_in, vg_in, vbe_in, vB, vG, vBe, vo_b1, vo_b2, vo_w2,
      enc_obs, value);

  act_encode_kernel<<<NROWS_ACT / 64, 256, 0, stream>>>(
      actE, vrows, counter, packW,
      pb_in, pg_in, pbe_in, pB, pG, pBe, po_b1, po_b2,
      enc_obs, logits);
}

// Round 11
// 1043.301 us; speedup vs baseline: 1.2083x; 1.2083x over previous
//
#include <hip/hip_runtime.h>
#include <math.h>

// ---------------------------------------------------------------------------
// ActorCriticPolicy fused forward — FP16 in/out, fp32 internal (R6+ verified).
//   E=100, H=256, L=4 res blocks, B=1024, A=256.
//   d_out: logits (1024x256 fp16) then value (1024 fp16).
//
// R11: revert R10 (577 MB HBM, L2-thrash: per-wave-private B streams ->
// ~5% MfmaUtil ceiling, measured 4.9%). R9 was ALSO L2-B-bound: each B frag
// fed 2 MFMAs -> 445 B/cyc demand vs 56 supply -> 12.6% ceiling (measured
// 12.4%). Fix: 4 m-tiles per wave -> each B frag feeds 4 MFMAs (53 B/cyc
// demand ~ supply). Block = 128 rows x 256 cols, 8 waves = 2 row-groups x
// 4 col-groups; wave = 64 rows x 64 cols, acc[4][4] floatx4 = 64 VGPRs
// (R10-proven no-spill count). Barriers: 2/layer (R9-proven structure).
//
// Fragment layouts (R7-verified): A: m=lane&15, k=(lane>>4)*8+j;
// B: n=lane&15, k=(lane>>4)*8+j; C/D: col=lane&15, row=(lane>>4)*4+reg.
// Packed B layout (f16 units), per net [WIN | L0..L3 | W1 | (W2)]:
//   policy: 0 win(Kp128), 32768+l*65536, W1@294912 (16nt), W2@360448 (7nt)
//   value:  base 389120: win, layers, W1@+294912 (8nt). total 716800 f16.
// ---------------------------------------------------------------------------

typedef unsigned short u16;
typedef _Float16 f16;
typedef _Float16 half8 __attribute__((ext_vector_type(8)));
typedef float floatx4 __attribute__((ext_vector_type(4)));

#define E_DIM  100
#define H_DIM  256
#define NLAYER 4
#define BATCH  1024
#define NACT   256
#define NROWS_ACT (BATCH * NACT)
#define LN_EPS 1e-5f
#define LDW    264

#define NET_WL(l) (32768 + (l) * 65536)
#define NET_W1   294912
#define NET_W2P  360448
#define POL_SZ   389120
#define VAL_BASE POL_SZ
#define PACK_TOTAL (POL_SZ + 327680)

#define WS_VROWS   16
#define WS_ENCOBS  (16 + NROWS_ACT * 4)
#define WS_PACK    (WS_ENCOBS + BATCH * E_DIM * 4)

__device__ __forceinline__ u16 f2h_u16(float f) {
  union { u16 u; f16 h; } c; c.h = (f16)f; return c.u;
}

__global__ void compact_kernel(const int* __restrict__ mask, int n,
                               int* __restrict__ counter,
                               int* __restrict__ rows,
                               u16* __restrict__ logits)
{
  const int i = blockIdx.x * blockDim.x + threadIdx.x;
  if (i < n) {
    if (mask[i]) {
      const int p = atomicAdd(counter, 1);
      rows[p] = i;
    } else {
      logits[i] = (u16)0xFBFF;   // -65504, finite fp16 stand-in for -inf
    }
  }
}

__device__ __forceinline__ f16 pack_elem(const f16* __restrict__ W, int li,
                                         int K, int N, int Np)
{
  const int j = li & 7, lane = (li >> 3) & 63, tile = li >> 9;
  const int ntiles = Np >> 4;
  const int k0 = (tile / ntiles) * 32, n0 = (tile % ntiles) * 16;
  const int k = k0 + ((lane >> 4) << 3) + j, n = n0 + (lane & 15);
  return (k < K && n < N) ? W[k * N + n] : (f16)0.f;
}

// packs all 13 weight matrices; also zeroes the compaction counter
__global__ void pack_all_kernel(
    const f16* __restrict__ pw_in, const f16* __restrict__ pW,
    const f16* __restrict__ po_w1, const f16* __restrict__ po_w2,
    const f16* __restrict__ vw_in, const f16* __restrict__ vW,
    const f16* __restrict__ vo_w1, f16* __restrict__ dst,
    int* __restrict__ counter)
{
  const int i = blockIdx.x * blockDim.x + threadIdx.x;
  if (i == 0) *counter = 0;
  if (i >= PACK_TOTAL) return;
  f16 v;
  if (i < 32768)        v = pack_elem(pw_in, i, E_DIM, H_DIM, 256);
  else if (i < 294912) { const int r = i - 32768, l = r >> 16;
                         v = pack_elem(pW + (size_t)l * 65536, r & 65535, 256, 256, 256); }
  else if (i < 360448)  v = pack_elem(po_w1, i - 294912, 256, 256, 256);
  else if (i < 389120)  v = pack_elem(po_w2, i - 360448, 256, E_DIM, 112);
  else if (i < 421888)  v = pack_elem(vw_in, i - 389120, E_DIM, H_DIM, 256);
  else if (i < 684032) { const int r = i - 421888, l = r >> 16;
                         v = pack_elem(vW + (size_t)l * 65536, r & 65535, 256, 256, 256); }
  else                  v = pack_elem(vo_w1, i - 684032, 256, 128, 128);
  dst[i] = v;
}

// wave GEMM: MT m-tiles x NT n-tiles, KT k-steps of 32; B reused across MT.
template <int MT, int NT, int KT, int NTALL>
__device__ __forceinline__ void wgemm(
    const f16* __restrict__ pw, const f16* __restrict__ h16,
    int row_base, int q, int l15, int lane, int nt_base,
    floatx4 (*acc)[NT])
{
  const f16* pl = pw + (size_t)nt_base * 512 + lane * 8;
#pragma unroll
  for (int k = 0; k < KT; ++k) {
    half8 a[MT];
#pragma unroll
    for (int mt = 0; mt < MT; ++mt)
      a[mt] = *(const half8*)(h16 + (row_base + mt * 16 + l15) * LDW + k * 32 + q * 8);
#pragma unroll
    for (int t = 0; t < NT; ++t) {
      const half8 b = *(const half8*)(pl + ((size_t)k * NTALL + t) * 512);
#pragma unroll
      for (int mt = 0; mt < MT; ++mt)
        acc[mt][t] = __builtin_amdgcn_mfma_f32_16x16x32_f16(a[mt], b, acc[mt][t], 0, 0, 0);
    }
  }
}

// trunk: input layer + NLAYER residual layers. R16: f16 residual stream.
template <bool R16>
__device__ __forceinline__ void run_trunk(
    const f16* __restrict__ packN,
    const f16* __restrict__ b_in, const f16* __restrict__ g_in, const f16* __restrict__ be_in,
    const f16* __restrict__ Br, const f16* __restrict__ Gr, const f16* __restrict__ Ber,
    f16* __restrict__ h16, float (*red)[4][2],
    floatx4 (*acc)[4], float* __restrict__ resf, f16* __restrict__ res16,
    int row_base, int q, int l15, int cg, int n0)
{
  const int lane15shift = 0; (void)lane15shift;
#pragma unroll 1
  for (int l = 0; l <= NLAYER; ++l) {
    const f16 *pw, *bias, *g, *be;
    if (l == 0) { pw = packN; bias = b_in; g = g_in; be = be_in; }
    else {
      pw = packN + NET_WL(l - 1); bias = Br + (l - 1) * H_DIM;
      g = Gr + (l - 1) * H_DIM;   be = Ber + (l - 1) * H_DIM;
    }
#pragma unroll
    for (int t = 0; t < 4; ++t) {
      const float bv = (float)bias[n0 + t * 16 + l15];
#pragma unroll
      for (int mt = 0; mt < 4; ++mt)
        acc[mt][t] = (floatx4){bv, bv, bv, bv};
    }
    if (l == 0) wgemm<4, 4, 4, 16>(pw, h16, row_base, q, l15, 0, cg * 4, acc);
    else        wgemm<4, 4, 8, 16>(pw, h16, row_base, q, l15, 0, cg * 4, acc);

    // LN partials over this wave's 64 cols, per row (mt, reg)
#pragma unroll
    for (int mt = 0; mt < 4; ++mt)
#pragma unroll
      for (int reg = 0; reg < 4; ++reg) {
        float s = 0.f, s2 = 0.f;
#pragma unroll
        for (int t = 0; t < 4; ++t) {
          const float v = fmaxf(acc[mt][t][reg], 0.f);
          s += v; s2 += v * v;
        }
#pragma unroll
        for (int off = 1; off < 16; off <<= 1) {
          s  += __shfl_xor(s, off, 64);
          s2 += __shfl_xor(s2, off, 64);
        }
        if (l15 == 0) {
          const int R = row_base + mt * 16 + q * 4 + reg;
          red[R][cg][0] = s; red[R][cg][1] = s2;
        }
      }
    __syncthreads();

#pragma unroll
    for (int mt = 0; mt < 4; ++mt)
#pragma unroll
      for (int reg = 0; reg < 4; ++reg) {
        const int R = row_base + mt * 16 + q * 4 + reg;
        const float s  = red[R][0][0] + red[R][1][0] + red[R][2][0] + red[R][3][0];
        const float s2 = red[R][0][1] + red[R][1][1] + red[R][2][1] + red[R][3][1];
        const float mean = s * (1.f / 256.f);
        const float var  = s2 * (1.f / 256.f) - mean * mean;
        const float rstd = 1.f / sqrtf(var + LN_EPS);
#pragma unroll
        for (int t = 0; t < 4; ++t) {
          const int col = n0 + t * 16 + l15;
          const float rg = rstd * (float)g[col];
          const float bm = (float)be[col] - mean * rg;
          const float v = fmaxf(acc[mt][t][reg], 0.f) * rg + bm;
          const int ri = (mt * 4 + t) * 4 + reg;
          float rp;
          if (l == 0) rp = 0.f;
          else rp = R16 ? (float)res16[ri] : resf[ri];
          const float r = rp + v;
          if (R16) res16[ri] = (f16)r; else resf[ri] = r;
          h16[R * LDW + col] = (f16)r;
        }
      }
    __syncthreads();
  }
}

// act-encode: 128 compacted rows per block -> logits
__global__ __launch_bounds__(512, 4)
void act_encode_kernel(
    const f16* __restrict__ xact,
    const int* __restrict__ vrows, const int* __restrict__ counter,
    const f16* __restrict__ packN,
    const f16* __restrict__ b_in, const f16* __restrict__ g_in, const f16* __restrict__ be_in,
    const f16* __restrict__ Br, const f16* __restrict__ Gr, const f16* __restrict__ Ber,
    const f16* __restrict__ b1, const f16* __restrict__ b2,
    const float* __restrict__ enc_obs_in,
    u16* __restrict__ logits)
{
  __shared__ __align__(16) f16 h16[128 * LDW];   // 67584 B
  __shared__ float red[128][4][2];               // 4096 B
  __shared__ int vrow_l[128];                    // 512 B

  const int tid  = threadIdx.x;
  const int lane = tid & 63;
  const int w    = tid >> 6;
  const int base = blockIdx.x * 128;
  const int count = *counter;
  if (base >= count) return;

  const int l15 = lane & 15, q = lane >> 4;
  const int rg = w & 1, cg = w >> 1;
  const int row_base = rg * 64, n0 = cg * 64;

  for (int idx = tid; idx < 128 * 128; idx += 512) {
    const int r = idx >> 7, c = idx & 127;
    const int gr = base + r;
    f16 v = (f16)0.f;
    if (c < E_DIM && gr < count) v = xact[(size_t)vrows[gr] * E_DIM + c];
    h16[r * LDW + c] = v;
  }
  if (tid < 128) vrow_l[tid] = (base + tid < count) ? vrows[base + tid] : 0;
  __syncthreads();

  floatx4 acc[4][4];
  f16 res16[64];
  run_trunk<true>(packN, b_in, g_in, be_in, Br, Gr, Ber, h16, red,
                  acc, nullptr, res16, row_base, q, l15, cg, n0);

  // head1: relu(h @ w1 + b1)
#pragma unroll
  for (int t = 0; t < 4; ++t) {
    const float bv = (float)b1[n0 + t * 16 + l15];
#pragma unroll
    for (int mt = 0; mt < 4; ++mt) acc[mt][t] = (floatx4){bv, bv, bv, bv};
  }
  wgemm<4, 4, 8, 16>(packN + NET_W1, h16, row_base, q, l15, 0, cg * 4, acc);
  __syncthreads();   // all reads of trunk h16 done
#pragma unroll
  for (int mt = 0; mt < 4; ++mt)
#pragma unroll
    for (int reg = 0; reg < 4; ++reg) {
      const int R = row_base + mt * 16 + q * 4 + reg;
#pragma unroll
      for (int t = 0; t < 4; ++t)
        h16[R * LDW + n0 + t * 16 + l15] = (f16)fmaxf(acc[mt][t][reg], 0.f);
    }
  __syncthreads();

  // head2: enc = h1 @ w2 + b2  (7 n-tiles, N pad 112)
  const int nt_base = cg * 2;
  const int ntc = (cg < 3) ? 2 : 1;
  floatx4 (*acc2)[2] = (floatx4(*)[2])acc;   // reuse registers? separate array:
  floatx4 a2[4][2];
#pragma unroll
  for (int t = 0; t < 2; ++t) {
    const int col = (nt_base + t) * 16 + l15;
    const float bv = (t < ntc && col < E_DIM) ? (float)b2[col] : 0.f;
#pragma unroll
    for (int mt = 0; mt < 4; ++mt) a2[mt][t] = (floatx4){bv, bv, bv, bv};
  }
  (void)acc2;
  if (cg < 3) wgemm<4, 2, 8, 7>(packN + NET_W2P, h16, row_base, q, l15, 0, nt_base, a2);
  else        wgemm<4, 1, 8, 7>(packN + NET_W2P, h16, row_base, q, l15, 0, nt_base,
                                (floatx4(*)[1])a2);
  __syncthreads();   // h16 reads done; red reusable

  // logit dot: partial per (row, cg) -> red -> sum
#pragma unroll
  for (int mt = 0; mt < 4; ++mt)
#pragma unroll
    for (int reg = 0; reg < 4; ++reg) {
      const int R = row_base + mt * 16 + q * 4 + reg;
      const int bb = vrow_l[R] >> 8;   // A = 256
      float p = 0.f;
#pragma unroll
      for (int t = 0; t < 2; ++t) {
        const int col = (nt_base + t) * 16 + l15;
        if (t < ntc && col < E_DIM)
          p += a2[mt][t][reg] * enc_obs_in[(size_t)bb * E_DIM + col];
      }
#pragma unroll
      for (int off = 1; off < 16; off <<= 1) p += __shfl_xor(p, off, 64);
      if (l15 == 0) red[R][cg][0] = p;
    }
  __syncthreads();
#pragma unroll
  for (int mt = 0; mt < 4; ++mt)
#pragma unroll
    for (int reg = 0; reg < 4; ++reg) {
      const int R = row_base + mt * 16 + q * 4 + reg;
      if (cg == 0 && l15 == 0 && base + R < count) {
        const float tot = red[R][0][0] + red[R][1][0] + red[R][2][0] + red[R][3][0];
        logits[vrow_l[R]] = f2h_u16(tot * 0.1f);   // 1/sqrt(100)
      }
    }
}

// merged: blocks 0..7 policy obs-encode -> enc_obs; 8..15 value net -> value
__global__ __launch_bounds__(512, 4)
void obs_value_kernel(
    const f16* __restrict__ obs,
    const f16* __restrict__ packP, const f16* __restrict__ packV,
    const f16* __restrict__ pb_in, const f16* __restrict__ pg_in, const f16* __restrict__ pbe_in,
    const f16* __restrict__ pB, const f16* __restrict__ pG, const f16* __restrict__ pBe,
    const f16* __restrict__ po_b1, const f16* __restrict__ po_b2,
    const f16* __restrict__ vb_in, const f16* __restrict__ vg_in, const f16* __restrict__ vbe_in,
    const f16* __restrict__ vB, const f16* __restrict__ vG, const f16* __restrict__ vBe,
    const f16* __restrict__ vo_b1, const f16* __restrict__ vo_b2, const f16* __restrict__ vo_w2,
    float* __restrict__ enc_obs_out, u16* __restrict__ value_out)
{
  __shared__ __align__(16) f16 h16[128 * LDW];
  __shared__ float red[128][4][2];

  const int tid  = threadIdx.x;
  const int lane = tid & 63;
  const int w    = tid >> 6;
  const bool isv = blockIdx.x >= 8;
  const int base = (isv ? (blockIdx.x - 8) : blockIdx.x) * 128;

  const int l15 = lane & 15, q = lane >> 4;
  const int rg = w & 1, cg = w >> 1;
  const int row_base = rg * 64, n0 = cg * 64;

  for (int idx = tid; idx < 128 * 128; idx += 512) {
    const int r = idx >> 7, c = idx & 127;
    h16[r * LDW + c] = (c < E_DIM) ? obs[(size_t)(base + r) * E_DIM + c] : (f16)0.f;
  }
  __syncthreads();

  floatx4 acc[4][4];

  if (!isv) {
    f16 res16[64];
    run_trunk<true>(packP, pb_in, pg_in, pbe_in, pB, pG, pBe, h16, red,
                    acc, nullptr, res16, row_base, q, l15, cg, n0);
    // head1
#pragma unroll
    for (int t = 0; t < 4; ++t) {
      const float bv = (float)po_b1[n0 + t * 16 + l15];
#pragma unroll
      for (int mt = 0; mt < 4; ++mt) acc[mt][t] = (floatx4){bv, bv, bv, bv};
    }
    wgemm<4, 4, 8, 16>(packP + NET_W1, h16, row_base, q, l15, 0, cg * 4, acc);
    __syncthreads();
#pragma unroll
    for (int mt = 0; mt < 4; ++mt)
#pragma unroll
      for (int reg = 0; reg < 4; ++reg) {
        const int R = row_base + mt * 16 + q * 4 + reg;
#pragma unroll
        for (int t = 0; t < 4; ++t)
          h16[R * LDW + n0 + t * 16 + l15] = (f16)fmaxf(acc[mt][t][reg], 0.f);
      }
    __syncthreads();
    // head2
    const int nt_base = cg * 2;
    const int ntc = (cg < 3) ? 2 : 1;
    floatx4 a2[4][2];
#pragma unroll
    for (int t = 0; t < 2; ++t) {
      const int col = (nt_base + t) * 16 + l15;
      const float bv = (t < ntc && col < E_DIM) ? (float)po_b2[col] : 0.f;
#pragma unroll
      for (int mt = 0; mt < 4; ++mt) a2[mt][t] = (floatx4){bv, bv, bv, bv};
    }
    if (cg < 3) wgemm<4, 2, 8, 7>(packP + NET_W2P, h16, row_base, q, l15, 0, nt_base, a2);
    else        wgemm<4, 1, 8, 7>(packP + NET_W2P, h16, row_base, q, l15, 0, nt_base,
                                  (floatx4(*)[1])a2);
#pragma unroll
    for (int mt = 0; mt < 4; ++mt)
#pragma unroll
      for (int reg = 0; reg < 4; ++reg) {
        const int R = row_base + mt * 16 + q * 4 + reg;
#pragma unroll
        for (int t = 0; t < 2; ++t) {
          const int col = (nt_base + t) * 16 + l15;
          if (t < ntc && col < E_DIM)
            enc_obs_out[(size_t)(base + R) * E_DIM + col] = a2[mt][t][reg];
        }
      }
  } else {
    float resf[64];
    run_trunk<false>(packV, vb_in, vg_in, vbe_in, vB, vG, vBe, h16, red,
                     acc, resf, nullptr, row_base, q, l15, cg, n0);
    // value head1: relu(h @ vo_w1 + vo_b1), N=128 (8 nt, 2 per cg)
    floatx4 a2[4][2];
#pragma unroll
    for (int t = 0; t < 2; ++t) {
      const float bv = (float)vo_b1[cg * 32 + t * 16 + l15];
#pragma unroll
      for (int mt = 0; mt < 4; ++mt) a2[mt][t] = (floatx4){bv, bv, bv, bv};
    }
    wgemm<4, 2, 8, 8>(packV + NET_W1, h16, row_base, q, l15, 0, cg * 2, a2);
    // head2: dot with vo_w2[128]
    float w2v[2];
#pragma unroll
    for (int t = 0; t < 2; ++t) w2v[t] = (float)vo_w2[cg * 32 + t * 16 + l15];
#pragma unroll
    for (int mt = 0; mt < 4; ++mt)
#pragma unroll
      for (int reg = 0; reg < 4; ++reg) {
        const int R = row_base + mt * 16 + q * 4 + reg;
        float p = fmaxf(a2[mt][0][reg], 0.f) * w2v[0] +
                  fmaxf(a2[mt][1][reg], 0.f) * w2v[1];
#pragma unroll
        for (int off = 1; off < 16; off <<= 1) p += __shfl_xor(p, off, 64);
        if (l15 == 0) red[R][cg][0] = p;
      }
    __syncthreads();
    const float b2v = (float)vo_b2[0];
#pragma unroll
    for (int mt = 0; mt < 4; ++mt)
#pragma unroll
      for (int reg = 0; reg < 4; ++reg) {
        const int R = row_base + mt * 16 + q * 4 + reg;
        if (cg == 0 && l15 == 0) {
          const float tot = red[R][0][0] + red[R][1][0] + red[R][2][0] + red[R][3][0];
          value_out[base + R] = f2h_u16(tot + b2v);
        }
      }
  }
}

// ============================ launch =======================================
extern "C" void kernel_launch(void* const* d_in, const int* in_sizes, int n_in,
                              void* d_out, int out_size, void* d_ws, size_t ws_size,
                              hipStream_t stream)
{
  const f16* obs   = (const f16*)d_in[0];
  const f16* actE  = (const f16*)d_in[1];
  const int* mask  = (const int*)d_in[2];
  const f16* pw_in = (const f16*)d_in[3];
  const f16* pb_in = (const f16*)d_in[4];
  const f16* pg_in = (const f16*)d_in[5];
  const f16* pbe_in= (const f16*)d_in[6];
  const f16* pW    = (const f16*)d_in[7];
  const f16* pB    = (const f16*)d_in[8];
  const f16* pG    = (const f16*)d_in[9];
  const f16* pBe   = (const f16*)d_in[10];
  const f16* po_w1 = (const f16*)d_in[11];
  const f16* po_b1 = (const f16*)d_in[12];
  const f16* po_w2 = (const f16*)d_in[13];
  const f16* po_b2 = (const f16*)d_in[14];
  const f16* vw_in = (const f16*)d_in[15];
  const f16* vb_in = (const f16*)d_in[16];
  const f16* vg_in = (const f16*)d_in[17];
  const f16* vbe_in= (const f16*)d_in[18];
  const f16* vW    = (const f16*)d_in[19];
  const f16* vB    = (const f16*)d_in[20];
  const f16* vG    = (const f16*)d_in[21];
  const f16* vBe   = (const f16*)d_in[22];
  const f16* vo_w1 = (const f16*)d_in[23];
  const f16* vo_b1 = (const f16*)d_in[24];
  const f16* vo_w2 = (const f16*)d_in[25];
  const f16* vo_b2 = (const f16*)d_in[26];

  u16* logits = (u16*)d_out;
  u16* value  = (u16*)d_out + NROWS_ACT;

  int*   counter = (int*)d_ws;
  int*   vrows   = (int*)((char*)d_ws + WS_VROWS);
  float* enc_obs = (float*)((char*)d_ws + WS_ENCOBS);
  f16*   packW   = (f16*)((char*)d_ws + WS_PACK);

  pack_all_kernel<<<(PACK_TOTAL + 255) / 256, 256, 0, stream>>>(
      pw_in, pW, po_w1, po_w2, vw_in, vW, vo_w1, packW, counter);
  compact_kernel<<<NROWS_ACT / 256, 256, 0, stream>>>(mask, NROWS_ACT, counter,
                                                      vrows, logits);
  obs_value_kernel<<<16, 512, 0, stream>>>(
      obs, packW, packW + VAL_BASE,
      pb_in, pg_in, pbe_in, pB, pG, pBe, po_b1, po_b2,
      vb_in, vg_in, vbe_in, vB, vG, vBe, vo_b1, vo_b2, vo_w2,
      enc_obs, value);
  act_encode_kernel<<<NROWS_ACT / 128, 512, 0, stream>>>(
      actE, vrows, counter, packW,
      pb_in, pg_in, pbe_in, pB, pG, pBe, po_b1, po_b2,
      enc_obs, logits);
}

// Round 12
// 705.733 us; speedup vs baseline: 1.7862x; 1.4783x over previous
//
#include <hip/hip_runtime.h>
#include <math.h>

// ---------------------------------------------------------------------------
// ActorCriticPolicy fused forward — FP16 in/out, fp32 internal (R6+ verified).
//   E=100, H=256, L=4 res blocks, B=1024, A=256.
//   d_out: logits (1024x256 fp16) then value (1024 fp16).
//
// R12: MT=4 under a 256-VGPR cap. R11/R10 both died of register spills
// (WRITE_SIZE 630MB/1GB scratch) — live set ~140 regs vs 128 cap. Fix:
// 256-thr blocks (4 waves) + __launch_bounds__(256,2) -> 256 VGPR, 2 blk/CU.
// Wave owns ALL 64 rows (4 m-tiles) x its 64 cols (4 n-tiles): 128 MFMA/layer,
// B fetched once per block per layer (~53 B/cyc at full rate ~ L2 supply).
// Plus: biases/gamma/beta staged into LDS once (8.4 KB) — R9's 12.4% ceiling
// was per-layer critical path incl. ~12 scalar L2 loads (~200cyc each).
//
// Fragment layouts (R7-verified): A: m=lane&15, k=(lane>>4)*8+j;
// B: n=lane&15, k=(lane>>4)*8+j; C/D: col=lane&15, row=(lane>>4)*4+reg.
// Packed B (f16 units): policy: 0 win(Kp128,16nt), 32768+l*65536 (16nt),
//   W1@294912 (16nt), W2@360448 (7nt); value: +389120: win, layers, W1 (8nt).
// ---------------------------------------------------------------------------

typedef unsigned short u16;
typedef _Float16 f16;
typedef _Float16 half8 __attribute__((ext_vector_type(8)));
typedef float floatx4 __attribute__((ext_vector_type(4)));

#define E_DIM  100
#define H_DIM  256
#define NLAYER 4
#define BATCH  1024
#define NACT   256
#define NROWS_ACT (BATCH * NACT)
#define LN_EPS 1e-5f
#define LDW    264

#define NET_WL(l) (32768 + (l) * 65536)
#define NET_W1   294912
#define NET_W2P  360448
#define POL_SZ   389120
#define VAL_BASE POL_SZ
#define PACK_TOTAL (POL_SZ + 327680)

#define WS_VROWS   16
#define WS_ENCOBS  (16 + NROWS_ACT * 4)
#define WS_PACK    (WS_ENCOBS + BATCH * E_DIM * 4)

// LDS param layout (f16 indices)
#define P_BIAS 0      // [5][256]
#define P_G    1280   // [5][256]
#define P_BE   2560   // [5][256]
#define P_B1   3840   // [256]  (value: vo_b1[128] @3840, vo_w2[128] @3968)
#define P_B2   4096   // [128] zero-padded
#define P_TOT  4224

__device__ __forceinline__ u16 f2h_u16(float f) {
  union { u16 u; f16 h; } c; c.h = (f16)f; return c.u;
}

__global__ void compact_kernel(const int* __restrict__ mask, int n,
                               int* __restrict__ counter,
                               int* __restrict__ rows,
                               u16* __restrict__ logits)
{
  const int i = blockIdx.x * blockDim.x + threadIdx.x;
  if (i < n) {
    if (mask[i]) {
      const int p = atomicAdd(counter, 1);
      rows[p] = i;
    } else {
      logits[i] = (u16)0xFBFF;   // -65504, finite fp16 stand-in for -inf
    }
  }
}

__device__ __forceinline__ f16 pack_elem(const f16* __restrict__ W, int li,
                                         int K, int N, int Np)
{
  const int j = li & 7, lane = (li >> 3) & 63, tile = li >> 9;
  const int ntiles = Np >> 4;
  const int k0 = (tile / ntiles) * 32, n0 = (tile % ntiles) * 16;
  const int k = k0 + ((lane >> 4) << 3) + j, n = n0 + (lane & 15);
  return (k < K && n < N) ? W[k * N + n] : (f16)0.f;
}

__global__ void pack_all_kernel(
    const f16* __restrict__ pw_in, const f16* __restrict__ pW,
    const f16* __restrict__ po_w1, const f16* __restrict__ po_w2,
    const f16* __restrict__ vw_in, const f16* __restrict__ vW,
    const f16* __restrict__ vo_w1, f16* __restrict__ dst,
    int* __restrict__ counter)
{
  const int i = blockIdx.x * blockDim.x + threadIdx.x;
  if (i == 0) *counter = 0;
  if (i >= PACK_TOTAL) return;
  f16 v;
  if (i < 32768)        v = pack_elem(pw_in, i, E_DIM, H_DIM, 256);
  else if (i < 294912) { const int r = i - 32768, l = r >> 16;
                         v = pack_elem(pW + (size_t)l * 65536, r & 65535, 256, 256, 256); }
  else if (i < 360448)  v = pack_elem(po_w1, i - 294912, 256, 256, 256);
  else if (i < 389120)  v = pack_elem(po_w2, i - 360448, 256, E_DIM, 112);
  else if (i < 421888)  v = pack_elem(vw_in, i - 389120, E_DIM, H_DIM, 256);
  else if (i < 684032) { const int r = i - 421888, l = r >> 16;
                         v = pack_elem(vW + (size_t)l * 65536, r & 65535, 256, 256, 256); }
  else                  v = pack_elem(vo_w1, i - 684032, 256, 128, 128);
  dst[i] = v;
}

// wave GEMM: 4 m-tiles x NT n-tiles, KT k-steps of 32; B reused across 4 MFMAs.
template <int NT, int KT, int NTALL>
__device__ __forceinline__ void wgemm(
    const f16* __restrict__ pw, const f16* __restrict__ h16,
    int q, int l15, int lane, int nt_base, floatx4 (*acc)[NT])
{
  const f16* pl = pw + (size_t)nt_base * 512 + lane * 8;
#pragma unroll
  for (int k = 0; k < KT; ++k) {
    half8 a[4];
#pragma unroll
    for (int mt = 0; mt < 4; ++mt)
      a[mt] = *(const half8*)(h16 + (mt * 16 + l15) * LDW + k * 32 + q * 8);
#pragma unroll
    for (int t = 0; t < NT; ++t) {
      const half8 b = *(const half8*)(pl + ((size_t)k * NTALL + t) * 512);
#pragma unroll
      for (int mt = 0; mt < 4; ++mt)
        acc[mt][t] = __builtin_amdgcn_mfma_f32_16x16x32_f16(a[mt], b, acc[mt][t], 0, 0, 0);
    }
  }
}

// trunk: input + NLAYER residual layers; params from LDS prm. R16: f16 residual.
template <bool R16>
__device__ __forceinline__ void run_trunk(
    const f16* __restrict__ packN, const f16* __restrict__ prm,
    f16* __restrict__ h16, float (*red)[4][2],
    floatx4 (*acc)[4], float* __restrict__ resf, f16* __restrict__ res16,
    int q, int l15, int lane, int cg, int n0)
{
#pragma unroll 1
  for (int l = 0; l <= NLAYER; ++l) {
    const f16* pw = (l == 0) ? packN : (packN + NET_WL(l - 1));
    const f16* bias = prm + P_BIAS + l * 256;
    const f16* g    = prm + P_G    + l * 256;
    const f16* be   = prm + P_BE   + l * 256;
#pragma unroll
    for (int t = 0; t < 4; ++t) {
      const float bv = (float)bias[n0 + t * 16 + l15];
#pragma unroll
      for (int mt = 0; mt < 4; ++mt)
        acc[mt][t] = (floatx4){bv, bv, bv, bv};
    }
    if (l == 0) wgemm<4, 4, 16>(pw, h16, q, l15, lane, cg * 4, acc);
    else        wgemm<4, 8, 16>(pw, h16, q, l15, lane, cg * 4, acc);

    // LN partials over this wave's 64 cols, per row (mt, reg)
#pragma unroll
    for (int mt = 0; mt < 4; ++mt)
#pragma unroll
      for (int reg = 0; reg < 4; ++reg) {
        float s = 0.f, s2 = 0.f;
#pragma unroll
        for (int t = 0; t < 4; ++t) {
          const float v = fmaxf(acc[mt][t][reg], 0.f);
          s += v; s2 += v * v;
        }
#pragma unroll
        for (int off = 1; off < 16; off <<= 1) {
          s  += __shfl_xor(s, off, 64);
          s2 += __shfl_xor(s2, off, 64);
        }
        if (l15 == 0) {
          const int R = mt * 16 + q * 4 + reg;
          red[R][cg][0] = s; red[R][cg][1] = s2;
        }
      }
    __syncthreads();

#pragma unroll
    for (int mt = 0; mt < 4; ++mt)
#pragma unroll
      for (int reg = 0; reg < 4; ++reg) {
        const int R = mt * 16 + q * 4 + reg;
        const float s  = red[R][0][0] + red[R][1][0] + red[R][2][0] + red[R][3][0];
        const float s2 = red[R][0][1] + red[R][1][1] + red[R][2][1] + red[R][3][1];
        const float mean = s * (1.f / 256.f);
        const float var  = s2 * (1.f / 256.f) - mean * mean;
        const float rstd = 1.f / sqrtf(var + LN_EPS);
#pragma unroll
        for (int t = 0; t < 4; ++t) {
          const int col = n0 + t * 16 + l15;
          const float rg = rstd * (float)g[col];
          const float bm = (float)be[col] - mean * rg;
          const float v = fmaxf(acc[mt][t][reg], 0.f) * rg + bm;
          const int ri = (mt * 4 + t) * 4 + reg;
          float rp;
          if (l == 0) rp = 0.f;
          else rp = R16 ? (float)res16[ri] : resf[ri];
          const float r = rp + v;
          if (R16) res16[ri] = (f16)r; else resf[ri] = r;
          h16[R * LDW + col] = (f16)r;
        }
      }
    __syncthreads();
  }
}

// policy heads: h1 = relu(h@W1+b1) -> h16; a2 = h1@W2+b2 (7 nt over 4 waves)
__device__ __forceinline__ void pol_heads(
    const f16* __restrict__ packN, const f16* __restrict__ prm,
    f16* __restrict__ h16, floatx4 (*acc)[4], floatx4 (*a2)[2],
    int q, int l15, int lane, int cg, int n0, int nt_base, int ntc)
{
#pragma unroll
  for (int t = 0; t < 4; ++t) {
    const float bv = (float)prm[P_B1 + n0 + t * 16 + l15];
#pragma unroll
    for (int mt = 0; mt < 4; ++mt) acc[mt][t] = (floatx4){bv, bv, bv, bv};
  }
  wgemm<4, 8, 16>(packN + NET_W1, h16, q, l15, lane, cg * 4, acc);
  __syncthreads();
#pragma unroll
  for (int mt = 0; mt < 4; ++mt)
#pragma unroll
    for (int reg = 0; reg < 4; ++reg) {
      const int R = mt * 16 + q * 4 + reg;
#pragma unroll
      for (int t = 0; t < 4; ++t)
        h16[R * LDW + n0 + t * 16 + l15] = (f16)fmaxf(acc[mt][t][reg], 0.f);
    }
  __syncthreads();

#pragma unroll
  for (int t = 0; t < 2; ++t) {
    const int col = (nt_base + t) * 16 + l15;
    const float bv = (t < ntc) ? (float)prm[P_B2 + col] : 0.f;
#pragma unroll
    for (int mt = 0; mt < 4; ++mt) a2[mt][t] = (floatx4){bv, bv, bv, bv};
  }
  if (ntc == 2) wgemm<2, 8, 7>(packN + NET_W2P, h16, q, l15, lane, nt_base, a2);
  else          wgemm<1, 8, 7>(packN + NET_W2P, h16, q, l15, lane, nt_base,
                               (floatx4(*)[1])a2);
  __syncthreads();   // h16 reads done; red reusable
}

// stage policy trunk+head params into LDS (256 threads)
__device__ __forceinline__ void stage_pol_params(
    f16* __restrict__ prm, int tid,
    const f16* __restrict__ b_in, const f16* __restrict__ g_in, const f16* __restrict__ be_in,
    const f16* __restrict__ Br, const f16* __restrict__ Gr, const f16* __restrict__ Ber,
    const f16* __restrict__ b1, const f16* __restrict__ b2)
{
  prm[P_BIAS + tid] = b_in[tid];
  prm[P_G    + tid] = g_in[tid];
  prm[P_BE   + tid] = be_in[tid];
#pragma unroll
  for (int l = 0; l < NLAYER; ++l) {
    prm[P_BIAS + 256 * (l + 1) + tid] = Br[l * 256 + tid];
    prm[P_G    + 256 * (l + 1) + tid] = Gr[l * 256 + tid];
    prm[P_BE   + 256 * (l + 1) + tid] = Ber[l * 256 + tid];
  }
  prm[P_B1 + tid] = b1[tid];
  if (tid < 128) prm[P_B2 + tid] = (tid < E_DIM) ? b2[tid] : (f16)0.f;
}

// act-encode: 64 compacted rows per block -> logits
__global__ __launch_bounds__(256, 2)
void act_encode_kernel(
    const f16* __restrict__ xact,
    const int* __restrict__ vrows, const int* __restrict__ counter,
    const f16* __restrict__ packN,
    const f16* __restrict__ b_in, const f16* __restrict__ g_in, const f16* __restrict__ be_in,
    const f16* __restrict__ Br, const f16* __restrict__ Gr, const f16* __restrict__ Ber,
    const f16* __restrict__ b1, const f16* __restrict__ b2,
    const float* __restrict__ enc_obs_in,
    u16* __restrict__ logits)
{
  __shared__ __align__(16) f16 h16[64 * LDW];   // 33792 B
  __shared__ float red[64][4][2];               // 2048 B
  __shared__ f16 prm[P_TOT];                    // 8448 B
  __shared__ int vrow_l[64];                    // 256 B

  const int tid  = threadIdx.x;
  const int lane = tid & 63;
  const int cg   = tid >> 6;
  const int base = blockIdx.x * 64;
  const int count = *counter;
  if (base >= count) return;

  const int l15 = lane & 15, q = lane >> 4;
  const int n0 = cg * 64;

  stage_pol_params(prm, tid, b_in, g_in, be_in, Br, Gr, Ber, b1, b2);
  if (tid < 64) vrow_l[tid] = (base + tid < count) ? vrows[base + tid] : 0;
  for (int idx = tid; idx < 64 * 128; idx += 256) {
    const int r = idx >> 7, c = idx & 127;
    const int gr = base + r;
    f16 v = (f16)0.f;
    if (c < E_DIM && gr < count) v = xact[(size_t)vrows[gr] * E_DIM + c];
    h16[r * LDW + c] = v;
  }
  __syncthreads();

  floatx4 acc[4][4];
  f16 res16[64];
  run_trunk<true>(packN, prm, h16, red, acc, nullptr, res16, q, l15, lane, cg, n0);

  const int nt_base = cg * 2;
  const int ntc = (cg < 3) ? 2 : 1;
  floatx4 a2[4][2];
  pol_heads(packN, prm, h16, acc, a2, q, l15, lane, cg, n0, nt_base, ntc);

  // logit dot: partial per (row, cg) -> red -> sum
#pragma unroll
  for (int mt = 0; mt < 4; ++mt)
#pragma unroll
    for (int reg = 0; reg < 4; ++reg) {
      const int R = mt * 16 + q * 4 + reg;
      const int bb = vrow_l[R] >> 8;   // A = 256
      float p = 0.f;
#pragma unroll
      for (int t = 0; t < 2; ++t) {
        const int col = (nt_base + t) * 16 + l15;
        if (t < ntc && col < E_DIM)
          p += a2[mt][t][reg] * enc_obs_in[(size_t)bb * E_DIM + col];
      }
#pragma unroll
      for (int off = 1; off < 16; off <<= 1) p += __shfl_xor(p, off, 64);
      if (l15 == 0) red[R][cg][0] = p;
    }
  __syncthreads();
#pragma unroll
  for (int mt = 0; mt < 4; ++mt)
#pragma unroll
    for (int reg = 0; reg < 4; ++reg) {
      const int R = mt * 16 + q * 4 + reg;
      if (cg == 0 && l15 == 0 && base + R < count) {
        const float tot = red[R][0][0] + red[R][1][0] + red[R][2][0] + red[R][3][0];
        logits[vrow_l[R]] = f2h_u16(tot * 0.1f);   // 1/sqrt(100)
      }
    }
}

// merged: blocks 0..15 policy obs-encode -> enc_obs; 16..31 value net -> value
__global__ __launch_bounds__(256, 2)
void obs_value_kernel(
    const f16* __restrict__ obs,
    const f16* __restrict__ packP, const f16* __restrict__ packV,
    const f16* __restrict__ pb_in, const f16* __restrict__ pg_in, const f16* __restrict__ pbe_in,
    const f16* __restrict__ pB, const f16* __restrict__ pG, const f16* __restrict__ pBe,
    const f16* __restrict__ po_b1, const f16* __restrict__ po_b2,
    const f16* __restrict__ vb_in, const f16* __restrict__ vg_in, const f16* __restrict__ vbe_in,
    const f16* __restrict__ vB, const f16* __restrict__ vG, const f16* __restrict__ vBe,
    const f16* __restrict__ vo_b1, const f16* __restrict__ vo_b2, const f16* __restrict__ vo_w2,
    float* __restrict__ enc_obs_out, u16* __restrict__ value_out)
{
  __shared__ __align__(16) f16 h16[64 * LDW];
  __shared__ float red[64][4][2];
  __shared__ f16 prm[P_TOT];

  const int tid  = threadIdx.x;
  const int lane = tid & 63;
  const int cg   = tid >> 6;
  const bool isv = blockIdx.x >= 16;
  const int base = (isv ? (blockIdx.x - 16) : blockIdx.x) * 64;

  const int l15 = lane & 15, q = lane >> 4;
  const int n0 = cg * 64;

  if (!isv) {
    stage_pol_params(prm, tid, pb_in, pg_in, pbe_in, pB, pG, pBe, po_b1, po_b2);
  } else {
    prm[P_BIAS + tid] = vb_in[tid];
    prm[P_G    + tid] = vg_in[tid];
    prm[P_BE   + tid] = vbe_in[tid];
#pragma unroll
    for (int l = 0; l < NLAYER; ++l) {
      prm[P_BIAS + 256 * (l + 1) + tid] = vB[l * 256 + tid];
      prm[P_G    + 256 * (l + 1) + tid] = vG[l * 256 + tid];
      prm[P_BE   + 256 * (l + 1) + tid] = vBe[l * 256 + tid];
    }
    if (tid < 128) { prm[P_B1 + tid] = vo_b1[tid]; prm[P_B1 + 128 + tid] = vo_w2[tid]; }
  }
  for (int idx = tid; idx < 64 * 128; idx += 256) {
    const int r = idx >> 7, c = idx & 127;
    h16[r * LDW + c] = (c < E_DIM) ? obs[(size_t)(base + r) * E_DIM + c] : (f16)0.f;
  }
  __syncthreads();

  floatx4 acc[4][4];

  if (!isv) {
    f16 res16[64];
    run_trunk<true>(packP, prm, h16, red, acc, nullptr, res16, q, l15, lane, cg, n0);
    const int nt_base = cg * 2;
    const int ntc = (cg < 3) ? 2 : 1;
    floatx4 a2[4][2];
    pol_heads(packP, prm, h16, acc, a2, q, l15, lane, cg, n0, nt_base, ntc);
#pragma unroll
    for (int mt = 0; mt < 4; ++mt)
#pragma unroll
      for (int reg = 0; reg < 4; ++reg) {
        const int R = mt * 16 + q * 4 + reg;
#pragma unroll
        for (int t = 0; t < 2; ++t) {
          const int col = (nt_base + t) * 16 + l15;
          if (t < ntc && col < E_DIM)
            enc_obs_out[(size_t)(base + R) * E_DIM + col] = a2[mt][t][reg];
        }
      }
  } else {
    float resf[64];
    run_trunk<false>(packV, prm, h16, red, acc, resf, nullptr, q, l15, lane, cg, n0);
    // value head1: relu(h @ vo_w1 + vo_b1), N=128 (8 nt, 2 per cg)
    floatx4 a2[4][2];
#pragma unroll
    for (int t = 0; t < 2; ++t) {
      const float bv = (float)prm[P_B1 + cg * 32 + t * 16 + l15];
#pragma unroll
      for (int mt = 0; mt < 4; ++mt) a2[mt][t] = (floatx4){bv, bv, bv, bv};
    }
    wgemm<2, 8, 8>(packV + NET_W1, h16, q, l15, lane, cg * 2, a2);
    // head2: dot with vo_w2[128] (staged at P_B1+128)
    float w2v[2];
#pragma unroll
    for (int t = 0; t < 2; ++t) w2v[t] = (float)prm[P_B1 + 128 + cg * 32 + t * 16 + l15];
#pragma unroll
    for (int mt = 0; mt < 4; ++mt)
#pragma unroll
      for (int reg = 0; reg < 4; ++reg) {
        const int R = mt * 16 + q * 4 + reg;
        float p = fmaxf(a2[mt][0][reg], 0.f) * w2v[0] +
                  fmaxf(a2[mt][1][reg], 0.f) * w2v[1];
#pragma unroll
        for (int off = 1; off < 16; off <<= 1) p += __shfl_xor(p, off, 64);
        if (l15 == 0) red[R][cg][0] = p;
      }
    __syncthreads();
    const float b2v = (float)vo_b2[0];
#pragma unroll
    for (int mt = 0; mt < 4; ++mt)
#pragma unroll
      for (int reg = 0; reg < 4; ++reg) {
        const int R = mt * 16 + q * 4 + reg;
        if (cg == 0 && l15 == 0) {
          const float tot = red[R][0][0] + red[R][1][0] + red[R][2][0] + red[R][3][0];
          value_out[base + R] = f2h_u16(tot + b2v);
        }
      }
  }
}

// ============================ launch =======================================
extern "C" void kernel_launch(void* const* d_in, const int* in_sizes, int n_in,
                              void* d_out, int out_size, void* d_ws, size_t ws_size,
                              hipStream_t stream)
{
  const f16* obs   = (const f16*)d_in[0];
  const f16* actE  = (const f16*)d_in[1];
  const int* mask  = (const int*)d_in[2];
  const f16* pw_in = (const f16*)d_in[3];
  const f16* pb_in = (const f16*)d_in[4];
  const f16* pg_in = (const f16*)d_in[5];
  const f16* pbe_in= (const f16*)d_in[6];
  const f16* pW    = (const f16*)d_in[7];
  const f16* pB    = (const f16*)d_in[8];
  const f16* pG    = (const f16*)d_in[9];
  const f16* pBe   = (const f16*)d_in[10];
  const f16* po_w1 = (const f16*)d_in[11];
  const f16* po_b1 = (const f16*)d_in[12];
  const f16* po_w2 = (const f16*)d_in[13];
  const f16* po_b2 = (const f16*)d_in[14];
  const f16* vw_in = (const f16*)d_in[15];
  const f16* vb_in = (const f16*)d_in[16];
  const f16* vg_in = (const f16*)d_in[17];
  const f16* vbe_in= (const f16*)d_in[18];
  const f16* vW    = (const f16*)d_in[19];
  const f16* vB    = (const f16*)d_in[20];
  const f16* vG    = (const f16*)d_in[21];
  const f16* vBe   = (const f16*)d_in[22];
  const f16* vo_w1 = (const f16*)d_in[23];
  const f16* vo_b1 = (const f16*)d_in[24];
  const f16* vo_w2 = (const f16*)d_in[25];
  const f16* vo_b2 = (const f16*)d_in[26];

  u16* logits = (u16*)d_out;
  u16* value  = (u16*)d_out + NROWS_ACT;

  int*   counter = (int*)d_ws;
  int*   vrows   = (int*)((char*)d_ws + WS_VROWS);
  float* enc_obs = (float*)((char*)d_ws + WS_ENCOBS);
  f16*   packW   = (f16*)((char*)d_ws + WS_PACK);

  pack_all_kernel<<<(PACK_TOTAL + 255) / 256, 256, 0, stream>>>(
      pw_in, pW, po_w1, po_w2, vw_in, vW, vo_w1, packW, counter);
  compact_kernel<<<NROWS_ACT / 256, 256, 0, stream>>>(mask, NROWS_ACT, counter,
                                                      vrows, logits);
  obs_value_kernel<<<32, 256, 0, stream>>>(
      obs, packW, packW + VAL_BASE,
      pb_in, pg_in, pbe_in, pB, pG, pBe, po_b1, po_b2,
      vb_in, vg_in, vbe_in, vB, vG, vBe, vo_b1, vo_b2, vo_w2,
      enc_obs, value);
  act_encode_kernel<<<NROWS_ACT / 64, 256, 0, stream>>>(
      actE, vrows, counter, packW,
      pb_in, pg_in, pbe_in, pB, pG, pBe, po_b1, po_b2,
      enc_obs, logits);
}